// Round 4
// baseline (198.218 us; speedup 1.0000x reference)
//
#include <hip/hip_runtime.h>

typedef __bf16 bf16;
typedef __bf16 bf16x8 __attribute__((ext_vector_type(8)));
typedef __bf16 bf16x4 __attribute__((ext_vector_type(4)));
typedef float f32x4 __attribute__((ext_vector_type(4)));

#define AS1(p) ((const __attribute__((address_space(1))) void*)(p))
#define AS3(p) ((__attribute__((address_space(3))) void*)(p))

__device__ __forceinline__ float sigm(float x) {
    return 1.f / (1.f + __expf(-x));
}
__device__ __forceinline__ float tanh_fast(float x) {
    float xx = fminf(fmaxf(x, -15.f), 15.f);
    float e = __expf(2.f * xx);
    return (e - 1.f) / (e + 1.f);
}
__device__ __forceinline__ bf16x8 pack8(float4 a, float4 b) {
    bf16x8 r;
    r[0] = (bf16)a.x; r[1] = (bf16)a.y; r[2] = (bf16)a.z; r[3] = (bf16)a.w;
    r[4] = (bf16)b.x; r[5] = (bf16)b.y; r[6] = (bf16)b.z; r[7] = (bf16)b.w;
    return r;
}

// ---------------------------------------------------------------------------
// Setup (verified R1): bf16 weight copies.
//  Wcat [256][224] = [Wp | Wa | Wv] along K.
//  Wih_p/Whh_p [768][256]: gate-permuted rows. Permuted col c = chunk*48 +
//  gate*16 + jj maps to old row gate*256 + (chunk*16 + jj).
// ---------------------------------------------------------------------------
__global__ __launch_bounds__(256) void setup_weights(
    const float* __restrict__ Wp, const float* __restrict__ Wa, const float* __restrict__ Wv,
    const float* __restrict__ W_ih, const float* __restrict__ b_ih,
    const float* __restrict__ W_hh, const float* __restrict__ b_hh,
    bf16* __restrict__ Wcat, bf16* __restrict__ Wih_p, bf16* __restrict__ Whh_p,
    float* __restrict__ bih_p, float* __restrict__ bhh_p)
{
    int idx = blockIdx.x * 256 + threadIdx.x;
    if (idx < 256 * 224) {
        int out = idx / 224, k = idx % 224;
        float v = (k < 128) ? Wp[out * 128 + k]
                : (k < 192) ? Wa[out * 64 + (k - 128)]
                            : Wv[out * 32 + (k - 192)];
        Wcat[idx] = (bf16)v;
    }
    int i2 = idx - 256 * 224;
    if (i2 >= 0 && i2 < 768 * 256) {
        int c = i2 >> 8, k = i2 & 255;
        int chunk = c / 48, gate = (c % 48) / 16, jj = c % 16;
        int oldrow = gate * 256 + chunk * 16 + jj;
        Wih_p[i2] = (bf16)W_ih[oldrow * 256 + k];
        Whh_p[i2] = (bf16)W_hh[oldrow * 256 + k];
        if (k == 0) { bih_p[c] = b_ih[oldrow]; bhh_p[c] = b_hh[oldrow]; }
    }
}

// ---------------------------------------------------------------------------
// K1 (verified R1): emb[slot][256] = x_cat(slot) @ Wcat^T + bias(type).
// ---------------------------------------------------------------------------
__global__ __launch_bounds__(256) void emb_kernel(
    const float* __restrict__ px, const float* __restrict__ ax_, const float* __restrict__ vx,
    const float* __restrict__ bp, const float* __restrict__ ba, const float* __restrict__ bv,
    const int* __restrict__ type_ids, const int* __restrict__ node_ids,
    const bf16* __restrict__ Wcat, bf16* __restrict__ emb)
{
    __shared__ bf16 At[32 * 232];
    __shared__ float biasl[768];
    const int tid = threadIdx.x;

    biasl[tid] = bp[tid];
    biasl[256 + tid] = ba[tid];
    biasl[512 + tid] = bv[tid];

    unsigned int* Az = (unsigned int*)At;
    #pragma unroll
    for (int i = 0; i < 15; i++) { int z = i * 256 + tid; if (z < 3712) Az[z] = 0u; }
    __syncthreads();

    const int slot0 = blockIdx.x * 32;
    {
        const int s = tid >> 3, g = tid & 7;
        const int slot = slot0 + s;
        const int t = type_ids[slot];
        const long n = (long)node_ids[slot];
        bf16* Arow = At + s * 232;
        if (t == 0) {
            const float4* src = (const float4*)(px + n * 128);
            float4 v0 = src[g * 4 + 0], v1 = src[g * 4 + 1], v2 = src[g * 4 + 2], v3 = src[g * 4 + 3];
            *(bf16x8*)(Arow + 16 * g) = pack8(v0, v1);
            *(bf16x8*)(Arow + 16 * g + 8) = pack8(v2, v3);
        } else if (t == 1) {
            const float4* src = (const float4*)(ax_ + n * 64);
            float4 v0 = src[g * 2 + 0], v1 = src[g * 2 + 1];
            *(bf16x8*)(Arow + 128 + 8 * g) = pack8(v0, v1);
        } else {
            float4 v0 = ((const float4*)(vx + n * 32))[g];
            bf16x4 r4; r4[0] = (bf16)v0.x; r4[1] = (bf16)v0.y; r4[2] = (bf16)v0.z; r4[3] = (bf16)v0.w;
            *(bf16x4*)(Arow + 192 + 4 * g) = r4;
        }
    }
    __syncthreads();

    const int w = tid >> 6, lane = tid & 63, l15 = lane & 15, l4 = lane >> 4;
    f32x4 zv = {0.f, 0.f, 0.f, 0.f};
    f32x4 acc[2][4];
    #pragma unroll
    for (int i = 0; i < 2; i++)
        #pragma unroll
        for (int j = 0; j < 4; j++) acc[i][j] = zv;

    #pragma unroll
    for (int k0 = 0; k0 < 224; k0 += 32) {
        bf16x8 a[2], b[4];
        #pragma unroll
        for (int am = 0; am < 2; am++) {
            int r = 16 * am + l15;
            a[am] = *(const bf16x8*)(At + r * 232 + k0 + 8 * l4);
        }
        #pragma unroll
        for (int bn = 0; bn < 4; bn++) {
            int o = 64 * w + 16 * bn + l15;
            b[bn] = *(const bf16x8*)(Wcat + o * 224 + k0 + 8 * l4);
        }
        #pragma unroll
        for (int am = 0; am < 2; am++)
            #pragma unroll
            for (int bn = 0; bn < 4; bn++)
                acc[am][bn] = __builtin_amdgcn_mfma_f32_16x16x32_bf16(a[am], b[bn], acc[am][bn], 0, 0, 0);
    }

    #pragma unroll
    for (int am = 0; am < 2; am++)
        #pragma unroll
        for (int bn = 0; bn < 4; bn++) {
            int o = 64 * w + 16 * bn + l15;
            #pragma unroll
            for (int r = 0; r < 4; r++) {
                int slot = slot0 + 16 * am + 4 * l4 + r;
                int t = type_ids[slot];
                emb[((size_t)slot << 8) + o] = (bf16)(acc[am][bn][r] + biasl[t * 256 + o]);
            }
        }
}

// ---------------------------------------------------------------------------
// K2 (verified R1): gx[32768][768(perm)] = emb @ Wih_p^T + bih_p   (bf16 out)
// ---------------------------------------------------------------------------
__global__ __launch_bounds__(256) void gx_kernel(
    const bf16* __restrict__ Am, const bf16* __restrict__ Wih_p,
    const float* __restrict__ bih_p, bf16* __restrict__ gx)
{
    __shared__ bf16 At[128 * 64];
    __shared__ bf16 Bt[96 * 64];
    const int tid = threadIdx.x;
    const int row0 = blockIdx.x * 128;
    const int c0 = blockIdx.y * 96;
    const int w = tid >> 6, lane = tid & 63, l15 = lane & 15, l4 = lane >> 4;
    const int wm = w >> 1, wn = w & 1;

    f32x4 zv = {0.f, 0.f, 0.f, 0.f};
    f32x4 acc[4][3];
    #pragma unroll
    for (int i = 0; i < 4; i++)
        #pragma unroll
        for (int j = 0; j < 3; j++) acc[i][j] = zv;

    for (int k0 = 0; k0 < 256; k0 += 64) {
        #pragma unroll
        for (int i = 0; i < 4; i++) {
            int g = i * 256 + tid; int r = g >> 3, s = g & 7;
            const bf16* src = Am + ((size_t)(row0 + r) << 8) + k0 + ((s ^ (r & 7)) << 3);
            __builtin_amdgcn_global_load_lds(AS1(src), AS3(At + g * 8), 16, 0, 0);
        }
        #pragma unroll
        for (int i = 0; i < 3; i++) {
            int g = i * 256 + tid; int r = g >> 3, s = g & 7;
            const bf16* src = Wih_p + ((size_t)(c0 + r) << 8) + k0 + ((s ^ (r & 7)) << 3);
            __builtin_amdgcn_global_load_lds(AS1(src), AS3(Bt + g * 8), 16, 0, 0);
        }
        __syncthreads();
        #pragma unroll
        for (int kk = 0; kk < 64; kk += 32) {
            int sbase = kk >> 3;
            bf16x8 a[4], b[3];
            #pragma unroll
            for (int am = 0; am < 4; am++) {
                int r = 64 * wm + 16 * am + l15;
                a[am] = *(const bf16x8*)(At + r * 64 + (((sbase + l4) ^ (r & 7)) << 3));
            }
            #pragma unroll
            for (int bn = 0; bn < 3; bn++) {
                int c = 48 * wn + 16 * bn + l15;
                b[bn] = *(const bf16x8*)(Bt + c * 64 + (((sbase + l4) ^ (c & 7)) << 3));
            }
            #pragma unroll
            for (int am = 0; am < 4; am++)
                #pragma unroll
                for (int bn = 0; bn < 3; bn++)
                    acc[am][bn] = __builtin_amdgcn_mfma_f32_16x16x32_bf16(a[am], b[bn], acc[am][bn], 0, 0, 0);
        }
        __syncthreads();
    }

    #pragma unroll
    for (int am = 0; am < 4; am++)
        #pragma unroll
        for (int bn = 0; bn < 3; bn++) {
            int c = c0 + 48 * wn + 16 * bn + l15;
            float bi = bih_p[c];
            #pragma unroll
            for (int r = 0; r < 4; r++) {
                int row = row0 + 64 * wm + 16 * am + 4 * l4 + r;
                gx[(size_t)row * 768 + c] = (bf16)(acc[am][bn][r] + bi);
            }
        }
}

// ---------------------------------------------------------------------------
// K3: fused 8-step GRU + classifier, NO grid sync.  Grid = 128 blocks x 256
// threads; block owns rows [bx*32, +32).  h: fp32 in registers (each thread
// owns fixed (row,j) pairs) + bf16 LDS mirror (swizzled) as MFMA A-operand.
// Whh [768][256] streamed from L2 each step in 24KB sub-chunks (192 cols x
// 64 k), double-buffered 2-phase pipeline.  LDS = 2*24K + 16K = 64KB.
// Wave w handles col-group g = ci*4 + w (48 cols = r|z|n for j in [g*16,+16)).
// R4 fix (rule #20): the sc chunk loop MUST be fully unrolled — runtime ci
// demoted hold[]/bh[] to scratch in R3 (~80us of local-memory latency).
// ---------------------------------------------------------------------------
__device__ __forceinline__ void stage_whh(bf16* dst, const bf16* Whh_p,
                                          int ci, int kh, int tid) {
    #pragma unroll
    for (int it = 0; it < 6; it++) {
        int gg = it * 256 + tid;
        int rr = gg >> 3, ss = gg & 7;
        const bf16* srcp = Whh_p + ((size_t)(ci * 192 + rr) << 8) + kh * 64
                         + ((ss ^ (rr & 7)) << 3);
        __builtin_amdgcn_global_load_lds(AS1(srcp), AS3(dst + gg * 8), 16, 0, 0);
    }
}

__global__ __launch_bounds__(256, 1) void gru_fused(
    const bf16* __restrict__ Whh_p, const float* __restrict__ bhh_p,
    const bf16* __restrict__ gx, const int* __restrict__ lengths,
    const float* __restrict__ Wc, const float* __restrict__ bc,
    float* __restrict__ out)
{
    __shared__ __attribute__((aligned(16))) bf16 Bt[2][192 * 64];  // 2 x 24KB
    __shared__ __attribute__((aligned(16))) bf16 hb[32 * 256];     // 16KB swizzled
    const int tid = threadIdx.x;
    const int w = tid >> 6, lane = tid & 63, l15 = lane & 15, l4 = lane >> 4;
    const int row0 = blockIdx.x * 32;

    int len[2][4];
    #pragma unroll
    for (int am = 0; am < 2; am++)
        #pragma unroll
        for (int r = 0; r < 4; r++)
            len[am][r] = lengths[row0 + 16 * am + 4 * l4 + r];

    float bh[4][3];
    #pragma unroll
    for (int ci = 0; ci < 4; ci++) {
        int g = ci * 4 + w;
        bh[ci][0] = bhh_p[g * 48 + l15];
        bh[ci][1] = bhh_p[g * 48 + 16 + l15];
        bh[ci][2] = bhh_p[g * 48 + 32 + l15];
    }

    float hold[2][4][4];   // [am][r][ci] — all indices compile-time (rule #20)

    // prologue: issue first Whh sub-chunk; overlap with step-0 epilogue (h=0)
    stage_whh(&Bt[0][0], Whh_p, 0, 0, tid);

    #pragma unroll
    for (int ci = 0; ci < 4; ci++) {
        int g = ci * 4 + w;
        #pragma unroll
        for (int am = 0; am < 2; am++)
            #pragma unroll
            for (int r = 0; r < 4; r++) {
                int row = row0 + 16 * am + 4 * l4 + r;
                const bf16* gxp = gx + ((size_t)(row * 8 + 0)) * 768 + g * 48 + l15;
                float xr = (float)gxp[0], xz = (float)gxp[16], xn = (float)gxp[32];
                float rr = sigm(xr + bh[ci][0]);
                float zz = sigm(xz + bh[ci][1]);
                float nn = tanh_fast(xn + rr * bh[ci][2]);
                hold[am][r][ci] = (0 < len[am][r]) ? (1.f - zz) * nn : 0.f;
            }
    }
    // write h -> hb (bf16, slot-swizzled: slot' = slot ^ (row&7))
    #pragma unroll
    for (int ci = 0; ci < 4; ci++) {
        int j = (ci * 4 + w) * 16 + l15;
        int slot = j >> 3, jo = j & 7;
        #pragma unroll
        for (int am = 0; am < 2; am++)
            #pragma unroll
            for (int r = 0; r < 4; r++) {
                int rowl = 16 * am + 4 * l4 + r;
                hb[rowl * 256 + ((slot ^ (rowl & 7)) << 3) + jo] = (bf16)hold[am][r][ci];
            }
    }
    __syncthreads();   // drains stage(0) too (vmcnt 0 + barrier)

    for (int l = 1; l < 8; l++) {
        f32x4 acc[2][3];
        #pragma unroll
        for (int sc = 0; sc < 16; sc++) {   // MUST unroll: ci/kh/cur static
            const int ci = sc >> 2, kh = sc & 3;
            const int cur = sc & 1;
            const int nsc = (sc + 1) & 15;
            if (l < 7 || sc < 15)
                stage_whh(&Bt[cur ^ 1][0], Whh_p, nsc >> 2, nsc & 3, tid);

            if (kh == 0) {
                f32x4 zvv = {0.f, 0.f, 0.f, 0.f};
                #pragma unroll
                for (int am = 0; am < 2; am++)
                    #pragma unroll
                    for (int bn = 0; bn < 3; bn++) acc[am][bn] = zvv;
            }
            #pragma unroll
            for (int kk = 0; kk < 2; kk++) {
                bf16x8 a[2], b[3];
                #pragma unroll
                for (int am = 0; am < 2; am++) {
                    int rowl = 16 * am + l15;
                    int t = kh * 8 + kk * 4 + l4;           // global k-slot
                    a[am] = *(const bf16x8*)(hb + rowl * 256 + ((t ^ (rowl & 7)) << 3));
                }
                #pragma unroll
                for (int bn = 0; bn < 3; bn++) {
                    int cl = w * 48 + bn * 16 + l15;
                    int s = (kk * 4 + l4) ^ (cl & 7);
                    b[bn] = *(const bf16x8*)(&Bt[cur][cl * 64 + (s << 3)]);
                }
                #pragma unroll
                for (int am = 0; am < 2; am++)
                    #pragma unroll
                    for (int bn = 0; bn < 3; bn++)
                        acc[am][bn] = __builtin_amdgcn_mfma_f32_16x16x32_bf16(a[am], b[bn], acc[am][bn], 0, 0, 0);
            }
            if (kh == 3) {
                int g = ci * 4 + w;
                #pragma unroll
                for (int am = 0; am < 2; am++)
                    #pragma unroll
                    for (int r = 0; r < 4; r++) {
                        int row = row0 + 16 * am + 4 * l4 + r;
                        const bf16* gxp = gx + ((size_t)(row * 8 + l)) * 768 + g * 48 + l15;
                        float xr = (float)gxp[0], xz = (float)gxp[16], xn = (float)gxp[32];
                        float rr = sigm(xr + acc[am][0][r] + bh[ci][0]);
                        float zz = sigm(xz + acc[am][1][r] + bh[ci][1]);
                        float nn = tanh_fast(xn + rr * (acc[am][2][r] + bh[ci][2]));
                        float hp = hold[am][r][ci];
                        hold[am][r][ci] = (l < len[am][r]) ? (1.f - zz) * nn + zz * hp : hp;
                    }
            }
            __syncthreads();
        }
        // publish new h to hb for next step's GEMM
        #pragma unroll
        for (int ci = 0; ci < 4; ci++) {
            int j = (ci * 4 + w) * 16 + l15;
            int slot = j >> 3, jo = j & 7;
            #pragma unroll
            for (int am = 0; am < 2; am++)
                #pragma unroll
                for (int r = 0; r < 4; r++) {
                    int rowl = 16 * am + 4 * l4 + r;
                    hb[rowl * 256 + ((slot ^ (rowl & 7)) << 3) + jo] = (bf16)hold[am][r][ci];
                }
        }
        __syncthreads();
    }

    // fused classifier: out[row0+rl][c] = h_final[rl] . Wc[c] + bc[c]
    float* hfin = (float*)&Bt[0][0];   // reuse freed B buffer: [32][260] fp32
    #pragma unroll
    for (int ci = 0; ci < 4; ci++) {
        int j = (ci * 4 + w) * 16 + l15;
        #pragma unroll
        for (int am = 0; am < 2; am++)
            #pragma unroll
            for (int r = 0; r < 4; r++)
                hfin[(16 * am + 4 * l4 + r) * 260 + j] = hold[am][r][ci];
    }
    __syncthreads();
    {
        int rl = tid >> 3, c = tid & 7;
        const float4* hr = (const float4*)(hfin + rl * 260);
        const float4* wr = (const float4*)(Wc + c * 256);
        float o = bc[c];
        #pragma unroll 8
        for (int k = 0; k < 64; k++) {
            float4 a_ = hr[k], b_ = wr[k];
            o += a_.x * b_.x + a_.y * b_.y + a_.z * b_.z + a_.w * b_.w;
        }
        out[(row0 + rl) * 8 + c] = o;
    }
}

extern "C" void kernel_launch(void* const* d_in, const int* in_sizes, int n_in,
                              void* d_out, int out_size, void* d_ws, size_t ws_size,
                              hipStream_t stream) {
    if (n_in < 18) return;
    const float* paper_x  = (const float*)d_in[0];
    const float* author_x = (const float*)d_in[1];
    const float* venue_x  = (const float*)d_in[2];
    const float* Wp   = (const float*)d_in[3];
    const float* bp   = (const float*)d_in[4];
    const float* Wa   = (const float*)d_in[5];
    const float* ba   = (const float*)d_in[6];
    const float* Wv   = (const float*)d_in[7];
    const float* bv   = (const float*)d_in[8];
    const float* W_ih = (const float*)d_in[9];
    const float* b_ih = (const float*)d_in[10];
    const float* W_hh = (const float*)d_in[11];
    const float* b_hh = (const float*)d_in[12];
    const float* Wc   = (const float*)d_in[13];
    const float* bc   = (const float*)d_in[14];
    const int* type_ids = (const int*)d_in[15];
    const int* node_ids = (const int*)d_in[16];
    const int* lengths  = (const int*)d_in[17];

    char* ws = (char*)d_ws;
    size_t off = 0;
    bf16* Wcat  = (bf16*)(ws + off); off += (size_t)256 * 224 * 2;
    bf16* Wih_p = (bf16*)(ws + off); off += (size_t)768 * 256 * 2;
    bf16* Whh_p = (bf16*)(ws + off); off += (size_t)768 * 256 * 2;
    float* bih_p = (float*)(ws + off); off += 768 * 4;
    float* bhh_p = (float*)(ws + off); off += 768 * 4;
    off = (off + 255) & ~(size_t)255;
    bf16* emb = (bf16*)(ws + off); off += (size_t)32768 * 256 * 2;
    bf16* gx  = (bf16*)(ws + off); off += (size_t)32768 * 768 * 2;
    if (ws_size < off) return;

    setup_weights<<<992, 256, 0, stream>>>(Wp, Wa, Wv, W_ih, b_ih, W_hh, b_hh,
                                           Wcat, Wih_p, Whh_p, bih_p, bhh_p);
    emb_kernel<<<1024, 256, 0, stream>>>(paper_x, author_x, venue_x, bp, ba, bv,
                                         type_ids, node_ids, Wcat, emb);
    gx_kernel<<<dim3(256, 8), 256, 0, stream>>>(emb, Wih_p, bih_p, gx);
    gru_fused<<<128, 256, 0, stream>>>(Whh_p, bhh_p, gx, lengths, Wc, bc,
                                       (float*)d_out);
}

// Round 5
// 118.853 us; speedup vs baseline: 1.6678x; 1.6678x over previous
//
#include <hip/hip_runtime.h>

typedef __bf16 bf16;
typedef __bf16 bf16x8 __attribute__((ext_vector_type(8)));
typedef __bf16 bf16x4 __attribute__((ext_vector_type(4)));
typedef float f32x4 __attribute__((ext_vector_type(4)));

#define AS1(p) ((const __attribute__((address_space(1))) void*)(p))
#define AS3(p) ((__attribute__((address_space(3))) void*)(p))

__device__ __forceinline__ float sigm(float x) {
    return 1.f / (1.f + __expf(-x));
}
__device__ __forceinline__ float tanh_fast(float x) {
    float xx = fminf(fmaxf(x, -15.f), 15.f);
    float e = __expf(2.f * xx);
    return (e - 1.f) / (e + 1.f);
}
__device__ __forceinline__ bf16x8 pack8(float4 a, float4 b) {
    bf16x8 r;
    r[0] = (bf16)a.x; r[1] = (bf16)a.y; r[2] = (bf16)a.z; r[3] = (bf16)a.w;
    r[4] = (bf16)b.x; r[5] = (bf16)b.y; r[6] = (bf16)b.z; r[7] = (bf16)b.w;
    return r;
}

// ---------------------------------------------------------------------------
// Setup (verified R1): bf16 weight copies.
//  Wcat [256][224] = [Wp | Wa | Wv] along K.
//  Wih_p/Whh_p [768][256]: gate-permuted rows. Permuted col c = chunk*48 +
//  gate*16 + jj maps to old row gate*256 + (chunk*16 + jj).
// ---------------------------------------------------------------------------
__global__ __launch_bounds__(256) void setup_weights(
    const float* __restrict__ Wp, const float* __restrict__ Wa, const float* __restrict__ Wv,
    const float* __restrict__ W_ih, const float* __restrict__ b_ih,
    const float* __restrict__ W_hh, const float* __restrict__ b_hh,
    bf16* __restrict__ Wcat, bf16* __restrict__ Wih_p, bf16* __restrict__ Whh_p,
    float* __restrict__ bih_p, float* __restrict__ bhh_p)
{
    int idx = blockIdx.x * 256 + threadIdx.x;
    if (idx < 256 * 224) {
        int out = idx / 224, k = idx % 224;
        float v = (k < 128) ? Wp[out * 128 + k]
                : (k < 192) ? Wa[out * 64 + (k - 128)]
                            : Wv[out * 32 + (k - 192)];
        Wcat[idx] = (bf16)v;
    }
    int i2 = idx - 256 * 224;
    if (i2 >= 0 && i2 < 768 * 256) {
        int c = i2 >> 8, k = i2 & 255;
        int chunk = c / 48, gate = (c % 48) / 16, jj = c % 16;
        int oldrow = gate * 256 + chunk * 16 + jj;
        Wih_p[i2] = (bf16)W_ih[oldrow * 256 + k];
        Whh_p[i2] = (bf16)W_hh[oldrow * 256 + k];
        if (k == 0) { bih_p[c] = b_ih[oldrow]; bhh_p[c] = b_hh[oldrow]; }
    }
}

// ---------------------------------------------------------------------------
// K1 (verified R1): emb[slot][256] = x_cat(slot) @ Wcat^T + bias(type).
// ---------------------------------------------------------------------------
__global__ __launch_bounds__(256) void emb_kernel(
    const float* __restrict__ px, const float* __restrict__ ax_, const float* __restrict__ vx,
    const float* __restrict__ bp, const float* __restrict__ ba, const float* __restrict__ bv,
    const int* __restrict__ type_ids, const int* __restrict__ node_ids,
    const bf16* __restrict__ Wcat, bf16* __restrict__ emb)
{
    __shared__ bf16 At[32 * 232];
    __shared__ float biasl[768];
    const int tid = threadIdx.x;

    biasl[tid] = bp[tid];
    biasl[256 + tid] = ba[tid];
    biasl[512 + tid] = bv[tid];

    unsigned int* Az = (unsigned int*)At;
    #pragma unroll
    for (int i = 0; i < 15; i++) { int z = i * 256 + tid; if (z < 3712) Az[z] = 0u; }
    __syncthreads();

    const int slot0 = blockIdx.x * 32;
    {
        const int s = tid >> 3, g = tid & 7;
        const int slot = slot0 + s;
        const int t = type_ids[slot];
        const long n = (long)node_ids[slot];
        bf16* Arow = At + s * 232;
        if (t == 0) {
            const float4* src = (const float4*)(px + n * 128);
            float4 v0 = src[g * 4 + 0], v1 = src[g * 4 + 1], v2 = src[g * 4 + 2], v3 = src[g * 4 + 3];
            *(bf16x8*)(Arow + 16 * g) = pack8(v0, v1);
            *(bf16x8*)(Arow + 16 * g + 8) = pack8(v2, v3);
        } else if (t == 1) {
            const float4* src = (const float4*)(ax_ + n * 64);
            float4 v0 = src[g * 2 + 0], v1 = src[g * 2 + 1];
            *(bf16x8*)(Arow + 128 + 8 * g) = pack8(v0, v1);
        } else {
            float4 v0 = ((const float4*)(vx + n * 32))[g];
            bf16x4 r4; r4[0] = (bf16)v0.x; r4[1] = (bf16)v0.y; r4[2] = (bf16)v0.z; r4[3] = (bf16)v0.w;
            *(bf16x4*)(Arow + 192 + 4 * g) = r4;
        }
    }
    __syncthreads();

    const int w = tid >> 6, lane = tid & 63, l15 = lane & 15, l4 = lane >> 4;
    f32x4 zv = {0.f, 0.f, 0.f, 0.f};
    f32x4 acc[2][4];
    #pragma unroll
    for (int i = 0; i < 2; i++)
        #pragma unroll
        for (int j = 0; j < 4; j++) acc[i][j] = zv;

    #pragma unroll
    for (int k0 = 0; k0 < 224; k0 += 32) {
        bf16x8 a[2], b[4];
        #pragma unroll
        for (int am = 0; am < 2; am++) {
            int r = 16 * am + l15;
            a[am] = *(const bf16x8*)(At + r * 232 + k0 + 8 * l4);
        }
        #pragma unroll
        for (int bn = 0; bn < 4; bn++) {
            int o = 64 * w + 16 * bn + l15;
            b[bn] = *(const bf16x8*)(Wcat + o * 224 + k0 + 8 * l4);
        }
        #pragma unroll
        for (int am = 0; am < 2; am++)
            #pragma unroll
            for (int bn = 0; bn < 4; bn++)
                acc[am][bn] = __builtin_amdgcn_mfma_f32_16x16x32_bf16(a[am], b[bn], acc[am][bn], 0, 0, 0);
    }

    #pragma unroll
    for (int am = 0; am < 2; am++)
        #pragma unroll
        for (int bn = 0; bn < 4; bn++) {
            int o = 64 * w + 16 * bn + l15;
            #pragma unroll
            for (int r = 0; r < 4; r++) {
                int slot = slot0 + 16 * am + 4 * l4 + r;
                int t = type_ids[slot];
                emb[((size_t)slot << 8) + o] = (bf16)(acc[am][bn][r] + biasl[t * 256 + o]);
            }
        }
}

// ---------------------------------------------------------------------------
// K2 (verified R1): gx[32768][768(perm)] = emb @ Wih_p^T + bih_p   (bf16 out)
// ---------------------------------------------------------------------------
__global__ __launch_bounds__(256) void gx_kernel(
    const bf16* __restrict__ Am, const bf16* __restrict__ Wih_p,
    const float* __restrict__ bih_p, bf16* __restrict__ gx)
{
    __shared__ bf16 At[128 * 64];
    __shared__ bf16 Bt[96 * 64];
    const int tid = threadIdx.x;
    const int row0 = blockIdx.x * 128;
    const int c0 = blockIdx.y * 96;
    const int w = tid >> 6, lane = tid & 63, l15 = lane & 15, l4 = lane >> 4;
    const int wm = w >> 1, wn = w & 1;

    f32x4 zv = {0.f, 0.f, 0.f, 0.f};
    f32x4 acc[4][3];
    #pragma unroll
    for (int i = 0; i < 4; i++)
        #pragma unroll
        for (int j = 0; j < 3; j++) acc[i][j] = zv;

    for (int k0 = 0; k0 < 256; k0 += 64) {
        #pragma unroll
        for (int i = 0; i < 4; i++) {
            int g = i * 256 + tid; int r = g >> 3, s = g & 7;
            const bf16* src = Am + ((size_t)(row0 + r) << 8) + k0 + ((s ^ (r & 7)) << 3);
            __builtin_amdgcn_global_load_lds(AS1(src), AS3(At + g * 8), 16, 0, 0);
        }
        #pragma unroll
        for (int i = 0; i < 3; i++) {
            int g = i * 256 + tid; int r = g >> 3, s = g & 7;
            const bf16* src = Wih_p + ((size_t)(c0 + r) << 8) + k0 + ((s ^ (r & 7)) << 3);
            __builtin_amdgcn_global_load_lds(AS1(src), AS3(Bt + g * 8), 16, 0, 0);
        }
        __syncthreads();
        #pragma unroll
        for (int kk = 0; kk < 64; kk += 32) {
            int sbase = kk >> 3;
            bf16x8 a[4], b[3];
            #pragma unroll
            for (int am = 0; am < 4; am++) {
                int r = 64 * wm + 16 * am + l15;
                a[am] = *(const bf16x8*)(At + r * 64 + (((sbase + l4) ^ (r & 7)) << 3));
            }
            #pragma unroll
            for (int bn = 0; bn < 3; bn++) {
                int c = 48 * wn + 16 * bn + l15;
                b[bn] = *(const bf16x8*)(Bt + c * 64 + (((sbase + l4) ^ (c & 7)) << 3));
            }
            #pragma unroll
            for (int am = 0; am < 4; am++)
                #pragma unroll
                for (int bn = 0; bn < 3; bn++)
                    acc[am][bn] = __builtin_amdgcn_mfma_f32_16x16x32_bf16(a[am], b[bn], acc[am][bn], 0, 0, 0);
        }
        __syncthreads();
    }

    #pragma unroll
    for (int am = 0; am < 4; am++)
        #pragma unroll
        for (int bn = 0; bn < 3; bn++) {
            int c = c0 + 48 * wn + 16 * bn + l15;
            float bi = bih_p[c];
            #pragma unroll
            for (int r = 0; r < 4; r++) {
                int row = row0 + 64 * wm + 16 * am + 4 * l4 + r;
                gx[(size_t)row * 768 + c] = (bf16)(acc[am][bn][r] + bi);
            }
        }
}

// ---------------------------------------------------------------------------
// K3a: step 0 gates-only (h0 = 0 -> gh = 0, hr/hz/hn = b_hh).  Writes h1.
// Thread = (row, chunk): reads 48 contiguous gx cols, writes 16 j's.
// ---------------------------------------------------------------------------
__global__ __launch_bounds__(256) void gru_step0(
    const float* __restrict__ bhh_p, const bf16* __restrict__ gx,
    const int* __restrict__ lengths, float* __restrict__ houtf,
    bf16* __restrict__ houtb)
{
    __shared__ float bl[768];
    const int tid = threadIdx.x;
    bl[tid] = bhh_p[tid];
    bl[256 + tid] = bhh_p[256 + tid];
    bl[512 + tid] = bhh_p[512 + tid];
    __syncthreads();

    const int idx = blockIdx.x * 256 + tid;
    const int row = idx >> 4, chunk = idx & 15;
    const int len0 = lengths[row];

    bf16 gv[48];
    const bf16* gxp = gx + ((size_t)(row * 8 + 0)) * 768 + chunk * 48;
    #pragma unroll
    for (int i = 0; i < 6; i++)
        *(bf16x8*)(gv + 8 * i) = *(const bf16x8*)(gxp + 8 * i);

    float hv[16];
    #pragma unroll
    for (int jj = 0; jj < 16; jj++) {
        float xr = (float)gv[jj], xz = (float)gv[16 + jj], xn = (float)gv[32 + jj];
        float rr = sigm(xr + bl[chunk * 48 + jj]);
        float zz = sigm(xz + bl[chunk * 48 + 16 + jj]);
        float nn = tanh_fast(xn + rr * bl[chunk * 48 + 32 + jj]);
        hv[jj] = (0 < len0) ? (1.f - zz) * nn : 0.f;
    }
    float* hf = houtf + ((size_t)row << 8) + chunk * 16;
    bf16* hb = houtb + ((size_t)row << 8) + chunk * 16;
    #pragma unroll
    for (int i = 0; i < 4; i++)
        *(float4*)(hf + 4 * i) = make_float4(hv[4 * i], hv[4 * i + 1], hv[4 * i + 2], hv[4 * i + 3]);
    #pragma unroll
    for (int i = 0; i < 2; i++) {
        bf16x8 v;
        #pragma unroll
        for (int q = 0; q < 8; q++) v[q] = (bf16)hv[8 * i + q];
        *(bf16x8*)(hb + 8 * i) = v;
    }
}

// ---------------------------------------------------------------------------
// K3b: one GRU step (steps 1..7).  R5 geometry: 64 rows x 96 perm-cols per
// block -> grid 64x8 = 512 blocks = 2 blocks/CU (TLP hides stage stalls).
// Waves 2x2, wave tile 32x48 (2x3 frags), K=256 in 4 chunks of 64.
// LDS 20KB.  Fused gate epilogue identical to R1 (verified).
// ---------------------------------------------------------------------------
__global__ __launch_bounds__(256, 2) void gru_kernel(
    const bf16* __restrict__ hin_b, const float* __restrict__ hin_f,
    const bf16* __restrict__ Whh_p, const float* __restrict__ bhh_p,
    const bf16* __restrict__ gx, const int* __restrict__ lengths,
    float* __restrict__ hout_f, bf16* __restrict__ hout_b, int step)
{
    __shared__ bf16 At[64 * 64];
    __shared__ bf16 Bt[96 * 64];
    const int tid = threadIdx.x;
    const int row0 = blockIdx.x * 64;
    const int c0 = blockIdx.y * 96;
    const int w = tid >> 6, lane = tid & 63, l15 = lane & 15, l4 = lane >> 4;
    const int wm = w >> 1, wn = w & 1;

    f32x4 zv = {0.f, 0.f, 0.f, 0.f};
    f32x4 acc[2][3];
    #pragma unroll
    for (int i = 0; i < 2; i++)
        #pragma unroll
        for (int j = 0; j < 3; j++) acc[i][j] = zv;

    for (int k0 = 0; k0 < 256; k0 += 64) {
        #pragma unroll
        for (int i = 0; i < 2; i++) {
            int g = i * 256 + tid; int r = g >> 3, s = g & 7;
            const bf16* src = hin_b + ((size_t)(row0 + r) << 8) + k0 + ((s ^ (r & 7)) << 3);
            __builtin_amdgcn_global_load_lds(AS1(src), AS3(At + g * 8), 16, 0, 0);
        }
        #pragma unroll
        for (int i = 0; i < 3; i++) {
            int g = i * 256 + tid; int r = g >> 3, s = g & 7;
            const bf16* src = Whh_p + ((size_t)(c0 + r) << 8) + k0 + ((s ^ (r & 7)) << 3);
            __builtin_amdgcn_global_load_lds(AS1(src), AS3(Bt + g * 8), 16, 0, 0);
        }
        __syncthreads();
        #pragma unroll
        for (int kk = 0; kk < 64; kk += 32) {
            int sbase = kk >> 3;
            bf16x8 a[2], b[3];
            #pragma unroll
            for (int am = 0; am < 2; am++) {
                int r = 32 * wm + 16 * am + l15;
                a[am] = *(const bf16x8*)(At + r * 64 + (((sbase + l4) ^ (r & 7)) << 3));
            }
            #pragma unroll
            for (int bn = 0; bn < 3; bn++) {
                int c = 48 * wn + 16 * bn + l15;
                b[bn] = *(const bf16x8*)(Bt + c * 64 + (((sbase + l4) ^ (c & 7)) << 3));
            }
            #pragma unroll
            for (int am = 0; am < 2; am++)
                #pragma unroll
                for (int bn = 0; bn < 3; bn++)
                    acc[am][bn] = __builtin_amdgcn_mfma_f32_16x16x32_bf16(a[am], b[bn], acc[am][bn], 0, 0, 0);
        }
        __syncthreads();
    }

    const int cbase = c0 + 48 * wn + l15;
    const float bh0 = bhh_p[cbase], bh1 = bhh_p[cbase + 16], bh2 = bhh_p[cbase + 32];
    const int j = ((blockIdx.y * 2 + wn) << 4) + l15;

    #pragma unroll
    for (int am = 0; am < 2; am++) {
        #pragma unroll
        for (int r = 0; r < 4; r++) {
            int row = row0 + 32 * wm + 16 * am + 4 * l4 + r;
            const bf16* gxp = gx + ((size_t)(row * 8 + step)) * 768 + cbase;
            float xr = (float)gxp[0], xz = (float)gxp[16], xn = (float)gxp[32];
            float rr = sigm(xr + acc[am][0][r] + bh0);
            float zz = sigm(xz + acc[am][1][r] + bh1);
            float nn = tanh_fast(xn + rr * (acc[am][2][r] + bh2));
            float hold = hin_f[((size_t)row << 8) + j];
            float hnew = (step < lengths[row]) ? ((1.f - zz) * nn + zz * hold) : hold;
            hout_f[((size_t)row << 8) + j] = hnew;
            hout_b[((size_t)row << 8) + j] = (bf16)hnew;
        }
    }
}

// ---------------------------------------------------------------------------
// K4 (verified R1): logits = h_final @ Wc^T + bc
// ---------------------------------------------------------------------------
__global__ __launch_bounds__(256) void cls_kernel(
    const float* __restrict__ h, const float* __restrict__ Wc,
    const float* __restrict__ bc, float* __restrict__ out)
{
    __shared__ float Wl[8 * 260];
    int tid = threadIdx.x;
    for (int i = tid; i < 2048; i += 256) { int c = i >> 8, k = i & 255; Wl[c * 260 + k] = Wc[i]; }
    __syncthreads();
    int o = blockIdx.x * 256 + tid;
    int row = o >> 3, c = o & 7;
    const float4* hr = (const float4*)(h + ((size_t)row << 8));
    const float* wr = Wl + c * 260;
    float acc1 = 0.f;
    #pragma unroll 8
    for (int k = 0; k < 64; k++) {
        float4 a = hr[k];
        float4 b = *(const float4*)(wr + 4 * k);
        acc1 += a.x * b.x + a.y * b.y + a.z * b.z + a.w * b.w;
    }
    out[o] = acc1 + bc[c];
}

extern "C" void kernel_launch(void* const* d_in, const int* in_sizes, int n_in,
                              void* d_out, int out_size, void* d_ws, size_t ws_size,
                              hipStream_t stream) {
    if (n_in < 18) return;
    const float* paper_x  = (const float*)d_in[0];
    const float* author_x = (const float*)d_in[1];
    const float* venue_x  = (const float*)d_in[2];
    const float* Wp   = (const float*)d_in[3];
    const float* bp   = (const float*)d_in[4];
    const float* Wa   = (const float*)d_in[5];
    const float* ba   = (const float*)d_in[6];
    const float* Wv   = (const float*)d_in[7];
    const float* bv   = (const float*)d_in[8];
    const float* W_ih = (const float*)d_in[9];
    const float* b_ih = (const float*)d_in[10];
    const float* W_hh = (const float*)d_in[11];
    const float* b_hh = (const float*)d_in[12];
    const float* Wc   = (const float*)d_in[13];
    const float* bc   = (const float*)d_in[14];
    const int* type_ids = (const int*)d_in[15];
    const int* node_ids = (const int*)d_in[16];
    const int* lengths  = (const int*)d_in[17];

    char* ws = (char*)d_ws;
    size_t off = 0;
    bf16* Wcat  = (bf16*)(ws + off); off += (size_t)256 * 224 * 2;
    bf16* Wih_p = (bf16*)(ws + off); off += (size_t)768 * 256 * 2;
    bf16* Whh_p = (bf16*)(ws + off); off += (size_t)768 * 256 * 2;
    float* bih_p = (float*)(ws + off); off += 768 * 4;
    float* bhh_p = (float*)(ws + off); off += 768 * 4;
    off = (off + 255) & ~(size_t)255;
    bf16* emb = (bf16*)(ws + off); off += (size_t)32768 * 256 * 2;
    bf16* gx  = (bf16*)(ws + off); off += (size_t)32768 * 768 * 2;
    float* h0f = (float*)(ws + off); off += (size_t)4096 * 256 * 4;
    bf16*  h0b = (bf16*)(ws + off);  off += (size_t)4096 * 256 * 2;
    float* h1f = (float*)(ws + off); off += (size_t)4096 * 256 * 4;
    bf16*  h1b = (bf16*)(ws + off);  off += (size_t)4096 * 256 * 2;
    if (ws_size < off) return;

    setup_weights<<<992, 256, 0, stream>>>(Wp, Wa, Wv, W_ih, b_ih, W_hh, b_hh,
                                           Wcat, Wih_p, Whh_p, bih_p, bhh_p);
    emb_kernel<<<1024, 256, 0, stream>>>(paper_x, author_x, venue_x, bp, ba, bv,
                                         type_ids, node_ids, Wcat, emb);
    gx_kernel<<<dim3(256, 8), 256, 0, stream>>>(emb, Wih_p, bih_p, gx);

    // step 0: h=0 -> gates-only, writes h1
    gru_step0<<<256, 256, 0, stream>>>(bhh_p, gx, lengths, h1f, h1b);
    // steps 1..7 ping-pong; final lands in h0
    for (int l = 1; l < 8; l++) {
        const bf16* hib = (l & 1) ? h1b : h0b;
        const float* hif = (l & 1) ? h1f : h0f;
        bf16* hob = (l & 1) ? h0b : h1b;
        float* hof = (l & 1) ? h0f : h1f;
        gru_kernel<<<dim3(64, 8), 256, 0, stream>>>(hib, hif, Whh_p, bhh_p, gx,
                                                    lengths, hof, hob, l);
    }
    cls_kernel<<<128, 256, 0, stream>>>(h0f, Wc, bc, (float*)d_out);
}